// Round 3
// baseline (385.250 us; speedup 1.0000x reference)
//
#include <hip/hip_runtime.h>
#include <math.h>

#define TOK_TOTAL 16384
#define D_MODEL   2048
#define NEXP      64
#define K4TOT     (D_MODEL / 4)      // 512 float4 per expert row
#define TAU       5e-4f

#define IDX_OFF   (TOK_TOTAL * NEXP)
#define LOSS_OFF  (IDX_OFF + TOK_TOTAL * 2)

// ws layout (floats): W_T4 [512][64] float4 | flags [16384] | cntp [256][64]
#define WS_FLAGS  (K4TOT * NEXP * 4)
#define WS_CNT    (WS_FLAGS + TOK_TOTAL)

// ---------------- K0: transpose W[64][2048] -> W_T4[k4][e] = float4(W[e][4k4..+3]) ----
__global__ __launch_bounds__(256, 1)
void wt_kernel(const float* __restrict__ W, float4* __restrict__ WT)
{
    __shared__ float L[64][36];
    const int t  = threadIdx.x;
    const int kc = blockIdx.x * 32;          // 64 blocks x 32 k each
    const int e  = t >> 2, c = (t & 3) * 8;
    float4 a = *(const float4*)(W + (long)e * D_MODEL + kc + c);
    float4 b = *(const float4*)(W + (long)e * D_MODEL + kc + c + 4);
    L[e][c+0]=a.x; L[e][c+1]=a.y; L[e][c+2]=a.z; L[e][c+3]=a.w;
    L[e][c+4]=b.x; L[e][c+5]=b.y; L[e][c+6]=b.z; L[e][c+7]=b.w;
    __syncthreads();
    const int k4 = t >> 5, e2 = (t & 31) * 2;   // 8 k4-rows x 64 experts
    const int kk = k4 * 4;
    float4 o0 = make_float4(L[e2  ][kk], L[e2  ][kk+1], L[e2  ][kk+2], L[e2  ][kk+3]);
    float4 o1 = make_float4(L[e2+1][kk], L[e2+1][kk+1], L[e2+1][kk+2], L[e2+1][kk+3]);
    WT[((long)(kc >> 2) + k4) * NEXP + e2    ] = o0;
    WT[((long)(kc >> 2) + k4) * NEXP + e2 + 1] = o1;
}

// ---------------- K1: fp32 GEMM, lane=expert, wave=8 tokens ----------------
#define TPB_TOK 32
#define TWAVE   8
#define TK4     32                     // k4 per LDS tile (=128 k)
#define NTILE   (K4TOT / TK4)          // 16

__global__ __launch_bounds__(256, 2)
void router_gemm(const float* __restrict__ x, const float4* __restrict__ WT,
                 float* __restrict__ out, float* __restrict__ flags)
{
    __shared__ float4 WTl[2 * TK4 * NEXP];       // 64 KB, double buffer
    __shared__ float  L[TPB_TOK][65];
    __shared__ int    s_i0[TPB_TOK], s_i1[TPB_TOK];
    __shared__ float  s_g0[TPB_TOK], s_g1[TPB_TOK];

    const int t    = threadIdx.x;
    const int lane = t & 63;
    const int wid  = __builtin_amdgcn_readfirstlane(t >> 6);
    const long tok0 = (long)blockIdx.x * TPB_TOK;
    const float* __restrict__ xb = x + (tok0 + wid * TWAVE) * D_MODEL;

    float acc[TWAVE];
    #pragma unroll
    for (int i = 0; i < TWAVE; ++i) acc[i] = 0.f;

    // prologue: stage tile 0 into buf 0
    #pragma unroll
    for (int j = 0; j < 8; ++j)
        WTl[t + 256 * j] = WT[t + 256 * j];
    __syncthreads();

    for (int kt = 0; kt < NTILE; ++kt) {
        const int buf = kt & 1;
        // T14 split: issue next tile's global loads before compute
        float4 r[8];
        const bool pre = (kt + 1 < NTILE);
        if (pre) {
            const float4* src = WT + (long)(kt + 1) * TK4 * NEXP;
            #pragma unroll
            for (int j = 0; j < 8; ++j) r[j] = src[t + 256 * j];
        }
        const float4* Wb = WTl + buf * (TK4 * NEXP);
        const int kbase = kt * TK4 * 4;
        #pragma unroll 4
        for (int k4 = 0; k4 < TK4; ++k4) {
            float4 wv = Wb[k4 * NEXP + lane];
            const int k = kbase + k4 * 4;
            #pragma unroll
            for (int i = 0; i < TWAVE; ++i) {
                float4 xv = *(const float4*)(xb + (long)i * D_MODEL + k);  // wave-uniform
                acc[i] = fmaf(xv.x, wv.x, acc[i]);
                acc[i] = fmaf(xv.y, wv.y, acc[i]);
                acc[i] = fmaf(xv.z, wv.z, acc[i]);
                acc[i] = fmaf(xv.w, wv.w, acc[i]);
            }
        }
        if (pre) {
            float4* dst = WTl + (buf ^ 1) * (TK4 * NEXP);
            #pragma unroll
            for (int j = 0; j < 8; ++j) dst[t + 256 * j] = r[j];
        }
        __syncthreads();
    }

    // logits -> LDS (conflict-free: stride 65)
    #pragma unroll
    for (int i = 0; i < TWAVE; ++i) L[wid * TWAVE + i][lane] = acc[i];
    __syncthreads();

    if (t < TPB_TOK) {
        float b0 = -1e30f, b1 = -1e30f, b2 = -1e30f;
        int i0 = 0, i1 = 0;
        for (int e = 0; e < NEXP; ++e) {
            float v = L[t][e];
            if (v > b0)      { b2 = b1; b1 = b0; i1 = i0; b0 = v; i0 = e; }
            else if (v > b1) { b2 = b1; b1 = v; i1 = e; }
            else if (v > b2) { b2 = v; }
        }
        float ex  = __expf(b1 - b0);
        float g0  = 1.f / (1.f + ex);
        long tok = tok0 + t;
        out[IDX_OFF + 2 * tok]     = (float)i0;
        out[IDX_OFF + 2 * tok + 1] = (float)i1;
        s_i0[t] = i0; s_i1[t] = i1; s_g0[t] = g0; s_g1[t] = ex * g0;
        flags[tok] = ((b0 - b1 < TAU) || (b1 - b2 < TAU)) ? 1.f : 0.f;
    }
    __syncthreads();

    // dense gate rows: 8 lanes per token, 8 floats each
    const int r8 = t >> 3, e0 = (t & 7) * 8;
    const int gi0 = s_i0[r8], gi1 = s_i1[r8];
    const float g0 = s_g0[r8], g1 = s_g1[r8];
    float v[8];
    #pragma unroll
    for (int j = 0; j < 8; ++j) {
        int e = e0 + j;
        v[j] = (e == gi0) ? g0 : ((e == gi1) ? g1 : 0.f);
    }
    float* orow = out + (tok0 + r8) * NEXP + e0;
    *(float4*)(orow)     = make_float4(v[0], v[1], v[2], v[3]);
    *(float4*)(orow + 4) = make_float4(v[4], v[5], v[6], v[7]);
}

// ---------------- K2: fp64 repair of flagged tokens (rare) ----------------
__global__ __launch_bounds__(256, 1)
void router_repair(const float* __restrict__ x, const float* __restrict__ W,
                   float* __restrict__ out, const float* __restrict__ flags)
{
    __shared__ double red[4][NEXP];
    __shared__ float  rg[2];
    __shared__ int    ri[2];
    const int t = threadIdx.x;
    const int e = t & 63;
    const int part = t >> 6;
    const long tok0 = (long)blockIdx.x * 64;

    for (int tt = 0; tt < 64; ++tt) {
        if (flags[tok0 + tt] == 0.f) continue;      // block-uniform
        const long tok = tok0 + tt;
        const float* xr = x + tok * D_MODEL;
        const float* wr = W + (long)e * D_MODEL;
        const int k0 = part * 512;
        double s = 0.0;
        for (int i = 0; i < 512; i += 4) {
            float4 xv = *(const float4*)(xr + k0 + i);
            float4 wv = *(const float4*)(wr + k0 + i);
            s = fma((double)xv.x, (double)wv.x, s);
            s = fma((double)xv.y, (double)wv.y, s);
            s = fma((double)xv.z, (double)wv.z, s);
            s = fma((double)xv.w, (double)wv.w, s);
        }
        red[part][e] = s;
        __syncthreads();
        if (t == 0) {
            double best = -1e300, sec = -1e300;
            int bi = 0, si = 0;
            for (int ee = 0; ee < NEXP; ++ee) {
                double vv = red[0][ee] + red[1][ee] + red[2][ee] + red[3][ee];
                if (vv > best)     { sec = best; si = bi; best = vv; bi = ee; }
                else if (vv > sec) { sec = vv; si = ee; }
            }
            double ex  = exp(sec - best);
            double inv = 1.0 / (1.0 + ex);
            out[IDX_OFF + 2 * tok]     = (float)bi;
            out[IDX_OFF + 2 * tok + 1] = (float)si;
            ri[0] = bi; ri[1] = si;
            rg[0] = (float)inv; rg[1] = (float)(ex * inv);
        }
        __syncthreads();
        if (t < 16) {
            const int bi = ri[0], si = ri[1];
            const float g0 = rg[0], g1 = rg[1];
            float vv[4];
            #pragma unroll
            for (int j = 0; j < 4; ++j) {
                int ee = t * 4 + j;
                vv[j] = (ee == bi) ? g0 : ((ee == si) ? g1 : 0.f);
            }
            *(float4*)(out + tok * NEXP + t * 4) = make_float4(vv[0], vv[1], vv[2], vv[3]);
        }
        __syncthreads();
    }
}

// ---------------- K3: per-block expert count partials from final gates ----------------
__global__ __launch_bounds__(256, 1)
void router_cnt(const float* __restrict__ gates, float* __restrict__ cntp)
{
    __shared__ float P[4][NEXP];
    const int t = threadIdx.x;
    const int e = t & 63, part = t >> 6;
    const long tok0 = (long)blockIdx.x * 64;
    float s = 0.f;
    for (int r = 0; r < 16; ++r)
        s += gates[(tok0 + part * 16 + r) * NEXP + e];
    P[part][e] = s;
    __syncthreads();
    if (t < NEXP)
        cntp[blockIdx.x * NEXP + t] = P[0][t] + P[1][t] + P[2][t] + P[3][t];
}

// ---------------- K4: load-balance loss ----------------
__global__ void router_loss(const float* __restrict__ cntp, float* __restrict__ out)
{
    __shared__ double sc[NEXP];
    const int e = threadIdx.x;
    double csum = 0.0;
    for (int b = 0; b < 256; ++b) csum += (double)cntp[b * NEXP + e];
    sc[e] = csum;
    __syncthreads();
    if (e == 0) {
        double tot = 0.0;
        for (int i = 0; i < NEXP; ++i) tot += sc[i];
        double loss = 0.0;
        for (int i = 0; i < NEXP; ++i) {
            double d = sc[i] / tot * (double)NEXP - 1.0;
            loss += d * d;
        }
        out[LOSS_OFF] = (float)(loss / NEXP);
    }
}

extern "C" void kernel_launch(void* const* d_in, const int* in_sizes, int n_in,
                              void* d_out, int out_size, void* d_ws, size_t ws_size,
                              hipStream_t stream)
{
    const float* x = (const float*)d_in[0];
    const float* W = (const float*)d_in[1];
    float* out   = (float*)d_out;
    float* ws    = (float*)d_ws;       // needs 640 KB
    float4* WT   = (float4*)ws;
    float* flags = ws + WS_FLAGS;
    float* cntp  = ws + WS_CNT;

    wt_kernel    <<<64,  256, 0, stream>>>(W, WT);
    router_gemm  <<<512, 256, 0, stream>>>(x, WT, out, flags);
    router_repair<<<256, 256, 0, stream>>>(x, W, out, flags);
    router_cnt   <<<256, 256, 0, stream>>>(out, cntp);
    router_loss  <<<1,   NEXP, 0, stream>>>(cntp, out);
}

// Round 5
// 223.407 us; speedup vs baseline: 1.7244x; 1.7244x over previous
//
#include <hip/hip_runtime.h>
#include <math.h>

#define TOK_TOTAL 16384
#define D_MODEL   2048
#define NEXP      64
#define TAU       5e-4f

#define BM        128          // tokens per gemm block
#define KC        32           // k per LDS chunk
#define KHALF     1024         // split-K: each block does half of K
#define NCHUNK    (KHALF / KC) // 32

#define IDX_OFF   (TOK_TOTAL * NEXP)
#define LOSS_OFF  (IDX_OFF + TOK_TOTAL * 2)

// ws layout (floats): partial1 [16384*64] | flags [16384] | cntp [256*64]
#define WS_FLAGS  (TOK_TOTAL * NEXP)
#define WS_CNT    (WS_FLAGS + TOK_TOTAL)

// ---------------- K1: fp32 split-K GEMM, classic LDS tile, 8x4 per thread ----
__global__ __launch_bounds__(256, 1)
void router_gemm(const float* __restrict__ x, const float* __restrict__ W,
                 float* __restrict__ p0, float* __restrict__ p1)
{
    __shared__ __align__(16) float Xl[2][BM][36];   // stride 36 floats: b128-aligned, bank-spread
    __shared__ __align__(16) float Wl[2][NEXP][36];

    const int t   = threadIdx.x;
    const int kh  = blockIdx.x & 1;          // K half
    const int tgb = blockIdx.x >> 1;         // token block 0..127
    const long tok0 = (long)tgb * BM;
    const int eg = (t >> 2) & 15;            // expert group: experts eg+16m
    const int tg = ((t >> 6) << 2) | (t & 3);// token group:  tokens  tg+16i
    const int srow = t >> 3;                 // staging row base (0..31)
    const int sk4  = t & 7;                  // staging k4 slot
    const long kb0 = (long)kh * KHALF;

    float acc[8][4];
    #pragma unroll
    for (int i = 0; i < 8; ++i)
        #pragma unroll
        for (int m = 0; m < 4; ++m) acc[i][m] = 0.f;

    // prologue: stage chunk 0 into buf 0 (coalesced: 8 lanes x 16B per row)
    {
        const long kb = kb0 + sk4 * 4;
        #pragma unroll
        for (int p = 0; p < 4; ++p)
            *(float4*)&Xl[0][srow + 32*p][sk4*4] =
                *(const float4*)(x + (tok0 + srow + 32*p) * D_MODEL + kb);
        #pragma unroll
        for (int p = 0; p < 2; ++p)
            *(float4*)&Wl[0][srow + 32*p][sk4*4] =
                *(const float4*)(W + (long)(srow + 32*p) * D_MODEL + kb);
    }
    __syncthreads();

    for (int it = 0; it < NCHUNK; ++it) {
        const int buf = it & 1;
        float4 xr[4], wr[2];
        const bool pre = (it + 1 < NCHUNK);
        if (pre) {   // T14: issue next chunk's global loads before compute
            const long kb = kb0 + (it + 1) * KC + sk4 * 4;
            #pragma unroll
            for (int p = 0; p < 4; ++p)
                xr[p] = *(const float4*)(x + (tok0 + srow + 32*p) * D_MODEL + kb);
            #pragma unroll
            for (int p = 0; p < 2; ++p)
                wr[p] = *(const float4*)(W + (long)(srow + 32*p) * D_MODEL + kb);
        }
        #pragma unroll
        for (int k4 = 0; k4 < 8; ++k4) {
            float4 wv[4];
            #pragma unroll
            for (int m = 0; m < 4; ++m)
                wv[m] = *(const float4*)&Wl[buf][eg + 16*m][k4*4];
            #pragma unroll
            for (int i = 0; i < 8; ++i) {
                float4 xv = *(const float4*)&Xl[buf][tg + 16*i][k4*4];
                #pragma unroll
                for (int m = 0; m < 4; ++m) {
                    acc[i][m] = fmaf(xv.x, wv[m].x, acc[i][m]);
                    acc[i][m] = fmaf(xv.y, wv[m].y, acc[i][m]);
                    acc[i][m] = fmaf(xv.z, wv[m].z, acc[i][m]);
                    acc[i][m] = fmaf(xv.w, wv[m].w, acc[i][m]);
                }
            }
        }
        if (pre) {   // write-late into the other buffer
            #pragma unroll
            for (int p = 0; p < 4; ++p)
                *(float4*)&Xl[buf^1][srow + 32*p][sk4*4] = xr[p];
            #pragma unroll
            for (int p = 0; p < 2; ++p)
                *(float4*)&Wl[buf^1][srow + 32*p][sk4*4] = wr[p];
        }
        __syncthreads();
    }

    float* dst = kh ? p1 : p0;
    #pragma unroll
    for (int i = 0; i < 8; ++i)
        #pragma unroll
        for (int m = 0; m < 4; ++m)
            dst[(tok0 + tg + 16*i) * NEXP + eg + 16*m] = acc[i][m];
}

// ---------------- K2: combine halves + top-3 + flags + idx + gates ----------
__global__ __launch_bounds__(256, 1)
void router_combine(const float* __restrict__ p0, const float* __restrict__ p1,
                    float* __restrict__ out, float* __restrict__ flags)
{
    __shared__ float L[64][65];
    __shared__ int   s_i0[64], s_i1[64];
    __shared__ float s_g0[64], s_g1[64];
    const int t = threadIdx.x;
    const long tok0 = (long)blockIdx.x * 64;
    const int r = t >> 2, q = t & 3;
    const float4* a4 = (const float4*)(p0 + tok0 * NEXP);
    const float4* b4 = (const float4*)(p1 + tok0 * NEXP);
    #pragma unroll
    for (int j = 0; j < 4; ++j) {
        int f = r * 16 + q + 4 * j;
        float4 a = a4[f], b = b4[f];
        float* Lp = &L[r][(q + 4 * j) * 4];
        Lp[0] = a.x + b.x; Lp[1] = a.y + b.y; Lp[2] = a.z + b.z; Lp[3] = a.w + b.w;
    }
    __syncthreads();

    if (t < 64) {
        float b0 = -1e30f, b1 = -1e30f, b2 = -1e30f;
        int i0 = 0, i1 = 0;
        for (int e = 0; e < NEXP; ++e) {
            float v = L[t][e];
            if (v > b0)      { b2 = b1; b1 = b0; i1 = i0; b0 = v; i0 = e; }
            else if (v > b1) { b2 = b1; b1 = v; i1 = e; }
            else if (v > b2) { b2 = v; }
        }
        float ex = __expf(b1 - b0);
        float g0 = 1.f / (1.f + ex);
        long tok = tok0 + t;
        out[IDX_OFF + 2 * tok]     = (float)i0;
        out[IDX_OFF + 2 * tok + 1] = (float)i1;
        s_i0[t] = i0; s_i1[t] = i1; s_g0[t] = g0; s_g1[t] = ex * g0;
        flags[tok] = ((b0 - b1 < TAU) || (b1 - b2 < TAU)) ? 1.f : 0.f;
    }
    __syncthreads();

    // gates: 4 lanes per token row, 16 floats each -> full 64x64 coverage
    const int r8 = t >> 2;            // token 0..63
    const int e0 = (t & 3) * 16;      // expert base
    const int gi0 = s_i0[r8], gi1 = s_i1[r8];
    const float g0 = s_g0[r8], g1 = s_g1[r8];
    float* orow = out + (tok0 + r8) * NEXP + e0;
    #pragma unroll
    for (int j4 = 0; j4 < 4; ++j4) {
        float v[4];
        #pragma unroll
        for (int j = 0; j < 4; ++j) {
            int e = e0 + j4 * 4 + j;
            v[j] = (e == gi0) ? g0 : ((e == gi1) ? g1 : 0.f);
        }
        *(float4*)(orow + j4 * 4) = make_float4(v[0], v[1], v[2], v[3]);
    }
}

// ---------------- K3: fp64 repair of flagged tokens (rare) ----------------
__global__ __launch_bounds__(256, 1)
void router_repair(const float* __restrict__ x, const float* __restrict__ W,
                   float* __restrict__ out, const float* __restrict__ flags)
{
    __shared__ double red[4][NEXP];
    __shared__ float  rg[2];
    __shared__ int    ri[2];
    const int t = threadIdx.x;
    const int e = t & 63;
    const int part = t >> 6;
    const long tok0 = (long)blockIdx.x * 64;

    for (int tt = 0; tt < 64; ++tt) {
        if (flags[tok0 + tt] == 0.f) continue;      // block-uniform
        const long tok = tok0 + tt;
        const float* xr = x + tok * D_MODEL;
        const float* wr = W + (long)e * D_MODEL;
        const int k0 = part * 512;
        double s = 0.0;
        for (int i = 0; i < 512; i += 4) {
            float4 xv = *(const float4*)(xr + k0 + i);
            float4 wv = *(const float4*)(wr + k0 + i);
            s = fma((double)xv.x, (double)wv.x, s);
            s = fma((double)xv.y, (double)wv.y, s);
            s = fma((double)xv.z, (double)wv.z, s);
            s = fma((double)xv.w, (double)wv.w, s);
        }
        red[part][e] = s;
        __syncthreads();
        if (t == 0) {
            double best = -1e300, sec = -1e300;
            int bi = 0, si = 0;
            for (int ee = 0; ee < NEXP; ++ee) {
                double vv = red[0][ee] + red[1][ee] + red[2][ee] + red[3][ee];
                if (vv > best)     { sec = best; si = bi; best = vv; bi = ee; }
                else if (vv > sec) { sec = vv; si = ee; }
            }
            double ex  = exp(sec - best);
            double inv = 1.0 / (1.0 + ex);
            out[IDX_OFF + 2 * tok]     = (float)bi;
            out[IDX_OFF + 2 * tok + 1] = (float)si;
            ri[0] = bi; ri[1] = si;
            rg[0] = (float)inv; rg[1] = (float)(ex * inv);
        }
        __syncthreads();
        if (t < 16) {
            const int bi = ri[0], si = ri[1];
            const float g0 = rg[0], g1 = rg[1];
            float vv[4];
            #pragma unroll
            for (int j = 0; j < 4; ++j) {
                int ee = t * 4 + j;
                vv[j] = (ee == bi) ? g0 : ((ee == si) ? g1 : 0.f);
            }
            *(float4*)(out + tok * NEXP + t * 4) = make_float4(vv[0], vv[1], vv[2], vv[3]);
        }
        __syncthreads();
    }
}

// ---------------- K4: per-block expert count partials from final gates -----
__global__ __launch_bounds__(256, 1)
void router_cnt(const float* __restrict__ gates, float* __restrict__ cntp)
{
    __shared__ float P[4][NEXP];
    const int t = threadIdx.x;
    const int e = t & 63, part = t >> 6;
    const long tok0 = (long)blockIdx.x * 64;
    float s = 0.f;
    for (int r = 0; r < 16; ++r)
        s += gates[(tok0 + part * 16 + r) * NEXP + e];
    P[part][e] = s;
    __syncthreads();
    if (t < NEXP)
        cntp[blockIdx.x * NEXP + t] = P[0][t] + P[1][t] + P[2][t] + P[3][t];
}

// ---------------- K5: load-balance loss ----------------
__global__ void router_loss(const float* __restrict__ cntp, float* __restrict__ out)
{
    __shared__ double sc[NEXP];
    const int e = threadIdx.x;
    double csum = 0.0;
    for (int b = 0; b < 256; ++b) csum += (double)cntp[b * NEXP + e];
    sc[e] = csum;
    __syncthreads();
    if (e == 0) {
        double tot = 0.0;
        for (int i = 0; i < NEXP; ++i) tot += sc[i];
        double loss = 0.0;
        for (int i = 0; i < NEXP; ++i) {
            double d = sc[i] / tot * (double)NEXP - 1.0;
            loss += d * d;
        }
        out[LOSS_OFF] = (float)(loss / NEXP);
    }
}

extern "C" void kernel_launch(void* const* d_in, const int* in_sizes, int n_in,
                              void* d_out, int out_size, void* d_ws, size_t ws_size,
                              hipStream_t stream)
{
    const float* x = (const float*)d_in[0];
    const float* W = (const float*)d_in[1];
    float* out   = (float*)d_out;
    float* ws    = (float*)d_ws;        // needs ~4.33 MB
    float* p0    = out;                 // kh=0 partial -> gates region (overwritten by K2)
    float* p1    = ws;                  // kh=1 partial
    float* flags = ws + WS_FLAGS;
    float* cntp  = ws + WS_CNT;

    router_gemm   <<<256, 256, 0, stream>>>(x, W, p0, p1);
    router_combine<<<256, 256, 0, stream>>>(p0, p1, out, flags);
    router_repair <<<256, 256, 0, stream>>>(x, W, out, flags);
    router_cnt    <<<256, 256, 0, stream>>>(out, cntp);
    router_loss   <<<1,   NEXP, 0, stream>>>(cntp, out);
}

// Round 6
// 148.562 us; speedup vs baseline: 2.5932x; 1.5038x over previous
//
#include <hip/hip_runtime.h>
#include <hip/hip_bf16.h>
#include <math.h>

#define TOK_TOTAL 16384
#define D_MODEL   2048
#define NEXP      64
#define BM        64               // tokens per block
#define KC        64               // k per LDS chunk
#define NCH       (D_MODEL / KC)   // 32
#define PAD       72               // bf16 elems per LDS row (144B, 16B-aligned)
#define TAU       1e-3f

#define IDX_OFF   (TOK_TOTAL * NEXP)
#define LOSS_OFF  (IDX_OFF + TOK_TOTAL * 2)

// ws layout (floats): flags [16384] | cntp [256*64]
#define WS_CNT    TOK_TOTAL

typedef __attribute__((ext_vector_type(8))) short short8_t;
typedef __attribute__((ext_vector_type(4))) float f32x4;

// ---------------- K1: split-bf16 MFMA GEMM + fused top-2/gates/flags ----------
__global__ __launch_bounds__(256, 1)
void router_gemm(const float* __restrict__ x, const float* __restrict__ W,
                 float* __restrict__ out, float* __restrict__ flags)
{
    // lds[buf*4 + {0:XH,1:XL,2:WH,3:WL}][row][k]
    __shared__ __align__(16) short lds[8][BM][PAD];   // 73728 B
    __shared__ int   s_i0[BM], s_i1[BM];
    __shared__ float s_g0[BM], s_g1[BM];

    const int t = threadIdx.x;
    const int w = t >> 6;         // wave 0..3 -> token strip w*16..+15
    const int l = t & 63;
    const long tok0 = (long)blockIdx.x * BM;

    const int sr = t >> 4;        // staging row base 0..15
    const int sc = (t & 15) * 4;  // staging k column (elems)

    f32x4 acc[4];
    #pragma unroll
    for (int nt = 0; nt < 4; ++nt) acc[nt] = (f32x4){0.f, 0.f, 0.f, 0.f};

    float4 xr[4], wr[4];

    auto LOADCH = [&](int ic) {
        const long k0 = (long)ic * KC;
        #pragma unroll
        for (int p = 0; p < 4; ++p) {
            xr[p] = *(const float4*)(x + (tok0 + sr + 16 * p) * D_MODEL + k0 + sc);
            wr[p] = *(const float4*)(W + (long)(sr + 16 * p) * D_MODEL + k0 + sc);
        }
    };

    auto STORECH = [&](int buf) {
        #pragma unroll
        for (int p = 0; p < 4; ++p) {
            const int row = sr + 16 * p;
            const float fx[4] = {xr[p].x, xr[p].y, xr[p].z, xr[p].w};
            const float fw[4] = {wr[p].x, wr[p].y, wr[p].z, wr[p].w};
            short xh[4], xl[4], wh[4], wl[4];
            #pragma unroll
            for (int j = 0; j < 4; ++j) {
                __hip_bfloat16 h = __float2bfloat16(fx[j]);
                xh[j] = __builtin_bit_cast(short, h);
                float r = fx[j] - __bfloat162float(h);
                xl[j] = __builtin_bit_cast(short, __float2bfloat16(r));
                __hip_bfloat16 g = __float2bfloat16(fw[j]);
                wh[j] = __builtin_bit_cast(short, g);
                float s = fw[j] - __bfloat162float(g);
                wl[j] = __builtin_bit_cast(short, __float2bfloat16(s));
            }
            *(short4*)(&lds[buf * 4 + 0][row][sc]) = make_short4(xh[0], xh[1], xh[2], xh[3]);
            *(short4*)(&lds[buf * 4 + 1][row][sc]) = make_short4(xl[0], xl[1], xl[2], xl[3]);
            *(short4*)(&lds[buf * 4 + 2][row][sc]) = make_short4(wh[0], wh[1], wh[2], wh[3]);
            *(short4*)(&lds[buf * 4 + 3][row][sc]) = make_short4(wl[0], wl[1], wl[2], wl[3]);
        }
    };

    auto COMPUTE = [&](int buf) {
        const short* XH = &lds[buf * 4 + 0][0][0];
        const short* XL = &lds[buf * 4 + 1][0][0];
        const short* WH = &lds[buf * 4 + 2][0][0];
        const short* WL = &lds[buf * 4 + 3][0][0];
        const int arow = w * 16 + (l & 15);
        #pragma unroll
        for (int s = 0; s < 2; ++s) {
            const int ke = s * 32 + (l >> 4) * 8;
            short8_t ah = *(const short8_t*)(XH + arow * PAD + ke);
            short8_t al = *(const short8_t*)(XL + arow * PAD + ke);
            #pragma unroll
            for (int nt = 0; nt < 4; ++nt) {
                const int brow = nt * 16 + (l & 15);
                short8_t bh = *(const short8_t*)(WH + brow * PAD + ke);
                short8_t bl = *(const short8_t*)(WL + brow * PAD + ke);
                acc[nt] = __builtin_amdgcn_mfma_f32_16x16x32_bf16(ah, bh, acc[nt], 0, 0, 0);
                acc[nt] = __builtin_amdgcn_mfma_f32_16x16x32_bf16(ah, bl, acc[nt], 0, 0, 0);
                acc[nt] = __builtin_amdgcn_mfma_f32_16x16x32_bf16(al, bh, acc[nt], 0, 0, 0);
            }
        }
    };

    // prologue
    LOADCH(0);
    STORECH(0);
    __syncthreads();

    for (int ic = 0; ic < NCH; ++ic) {
        const int buf = ic & 1;
        if (ic + 1 < NCH) LOADCH(ic + 1);   // T14: issue early
        COMPUTE(buf);
        __syncthreads();
        if (ic + 1 < NCH) STORECH(buf ^ 1); // write-late
        __syncthreads();
    }

    // ---- logits -> LDS (reuse buf0 area: 64*68*4 = 17408B <= 18432B) ----
    float* Lg = (float*)&lds[0][0][0];      // [64][68]
    #pragma unroll
    for (int nt = 0; nt < 4; ++nt)
        #pragma unroll
        for (int r = 0; r < 4; ++r)
            Lg[(w * 16 + (l >> 4) * 4 + r) * 68 + nt * 16 + (l & 15)] = acc[nt][r];
    __syncthreads();

    // ---- top-3 per token, flags, indices ----
    if (t < BM) {
        const float* lrow = Lg + t * 68;
        float b0 = -1e30f, b1 = -1e30f, b2 = -1e30f;
        int i0 = 0, i1 = 0;
        for (int e = 0; e < NEXP; ++e) {
            float v = lrow[e];
            if (v > b0)      { b2 = b1; b1 = b0; i1 = i0; b0 = v; i0 = e; }
            else if (v > b1) { b2 = b1; b1 = v; i1 = e; }
            else if (v > b2) { b2 = v; }
        }
        float ex = __expf(b1 - b0);
        float g0 = 1.f / (1.f + ex);
        long tok = tok0 + t;
        out[IDX_OFF + 2 * tok]     = (float)i0;
        out[IDX_OFF + 2 * tok + 1] = (float)i1;
        s_i0[t] = i0; s_i1[t] = i1; s_g0[t] = g0; s_g1[t] = ex * g0;
        flags[tok] = ((b0 - b1 < TAU) || (b1 - b2 < TAU)) ? 1.f : 0.f;
    }
    __syncthreads();

    // ---- dense gates: 4 lanes per token, 16 floats each ----
    const int r8 = t >> 2;
    const int e0 = (t & 3) * 16;
    const int gi0 = s_i0[r8], gi1 = s_i1[r8];
    const float g0 = s_g0[r8], g1 = s_g1[r8];
    float* orow = out + (tok0 + r8) * NEXP + e0;
    #pragma unroll
    for (int j4 = 0; j4 < 4; ++j4) {
        float v[4];
        #pragma unroll
        for (int j = 0; j < 4; ++j) {
            int e = e0 + j4 * 4 + j;
            v[j] = (e == gi0) ? g0 : ((e == gi1) ? g1 : 0.f);
        }
        *(float4*)(orow + j4 * 4) = make_float4(v[0], v[1], v[2], v[3]);
    }
}

// ---------------- K2: fp64 repair of flagged tokens (rare) ----------------
__global__ __launch_bounds__(256, 1)
void router_repair(const float* __restrict__ x, const float* __restrict__ W,
                   float* __restrict__ out, const float* __restrict__ flags)
{
    __shared__ double red[4][NEXP];
    __shared__ float  rg[2];
    __shared__ int    ri[2];
    const int t = threadIdx.x;
    const int e = t & 63;
    const int part = t >> 6;
    const long tok0 = (long)blockIdx.x * 64;

    for (int tt = 0; tt < 64; ++tt) {
        if (flags[tok0 + tt] == 0.f) continue;      // block-uniform
        const long tok = tok0 + tt;
        const float* xr = x + tok * D_MODEL;
        const float* wr = W + (long)e * D_MODEL;
        const int k0 = part * 512;
        double s = 0.0;
        for (int i = 0; i < 512; i += 4) {
            float4 xv = *(const float4*)(xr + k0 + i);
            float4 wv = *(const float4*)(wr + k0 + i);
            s = fma((double)xv.x, (double)wv.x, s);
            s = fma((double)xv.y, (double)wv.y, s);
            s = fma((double)xv.z, (double)wv.z, s);
            s = fma((double)xv.w, (double)wv.w, s);
        }
        red[part][e] = s;
        __syncthreads();
        if (t == 0) {
            double best = -1e300, sec = -1e300;
            int bi = 0, si = 0;
            for (int ee = 0; ee < NEXP; ++ee) {
                double vv = red[0][ee] + red[1][ee] + red[2][ee] + red[3][ee];
                if (vv > best)     { sec = best; si = bi; best = vv; bi = ee; }
                else if (vv > sec) { sec = vv; si = ee; }
            }
            double ex  = exp(sec - best);
            double inv = 1.0 / (1.0 + ex);
            out[IDX_OFF + 2 * tok]     = (float)bi;
            out[IDX_OFF + 2 * tok + 1] = (float)si;
            ri[0] = bi; ri[1] = si;
            rg[0] = (float)inv; rg[1] = (float)(ex * inv);
        }
        __syncthreads();
        if (t < 16) {
            const int bi = ri[0], si = ri[1];
            const float g0 = rg[0], g1 = rg[1];
            float vv[4];
            #pragma unroll
            for (int j = 0; j < 4; ++j) {
                int ee = t * 4 + j;
                vv[j] = (ee == bi) ? g0 : ((ee == si) ? g1 : 0.f);
            }
            *(float4*)(out + tok * NEXP + t * 4) = make_float4(vv[0], vv[1], vv[2], vv[3]);
        }
        __syncthreads();
    }
}

// ---------------- K3: per-block expert count partials from final gates -----
__global__ __launch_bounds__(256, 1)
void router_cnt(const float* __restrict__ gates, float* __restrict__ cntp)
{
    __shared__ float P[4][NEXP];
    const int t = threadIdx.x;
    const int e = t & 63, part = t >> 6;
    const long tok0 = (long)blockIdx.x * 64;
    float s = 0.f;
    for (int r = 0; r < 16; ++r)
        s += gates[(tok0 + part * 16 + r) * NEXP + e];
    P[part][e] = s;
    __syncthreads();
    if (t < NEXP)
        cntp[blockIdx.x * NEXP + t] = P[0][t] + P[1][t] + P[2][t] + P[3][t];
}

// ---------------- K4: load-balance loss ----------------
__global__ void router_loss(const float* __restrict__ cntp, float* __restrict__ out)
{
    __shared__ double sc[NEXP];
    const int e = threadIdx.x;
    double csum = 0.0;
    for (int b = 0; b < 256; ++b) csum += (double)cntp[b * NEXP + e];
    sc[e] = csum;
    __syncthreads();
    if (e == 0) {
        double tot = 0.0;
        for (int i = 0; i < NEXP; ++i) tot += sc[i];
        double loss = 0.0;
        for (int i = 0; i < NEXP; ++i) {
            double d = sc[i] / tot * (double)NEXP - 1.0;
            loss += d * d;
        }
        out[LOSS_OFF] = (float)(loss / NEXP);
    }
}

extern "C" void kernel_launch(void* const* d_in, const int* in_sizes, int n_in,
                              void* d_out, int out_size, void* d_ws, size_t ws_size,
                              hipStream_t stream)
{
    const float* x = (const float*)d_in[0];
    const float* W = (const float*)d_in[1];
    float* out   = (float*)d_out;
    float* ws    = (float*)d_ws;        // needs 128 KB
    float* flags = ws;
    float* cntp  = ws + WS_CNT;

    router_gemm  <<<TOK_TOTAL / BM, 256, 0, stream>>>(x, W, out, flags);
    router_repair<<<256, 256, 0, stream>>>(x, W, out, flags);
    router_cnt   <<<256, 256, 0, stream>>>(out, cntp);
    router_loss  <<<1,   NEXP, 0, stream>>>(cntp, out);
}

// Round 7
// 128.603 us; speedup vs baseline: 2.9956x; 1.1552x over previous
//
#include <hip/hip_runtime.h>
#include <hip/hip_bf16.h>
#include <math.h>

#define TOK_TOTAL 16384
#define D_MODEL   2048
#define NEXP      64
#define BM        64               // tokens per block
#define KC        64               // k per LDS chunk
#define KHALF     1024             // split-K: half of K per block
#define NCH       (KHALF / KC)     // 16
#define PAD       72               // bf16 elems per LDS row (144B, 16B-aligned)
#define TAU       1e-3f

#define IDX_OFF   (TOK_TOTAL * NEXP)
#define LOSS_OFF  (IDX_OFF + TOK_TOTAL * 2)

// ws layout (floats): p1 [16384*64] | cntp [256*64]
#define WS_CNT    (TOK_TOTAL * NEXP)

typedef __attribute__((ext_vector_type(8))) short short8_t;
typedef __attribute__((ext_vector_type(4))) float f32x4;

// ---------------- K1: split-bf16 MFMA GEMM, split-K x2, 1 barrier/chunk -------
__global__ __launch_bounds__(256, 2)
void router_gemm(const float* __restrict__ x, const float* __restrict__ W,
                 float* __restrict__ p0, float* __restrict__ p1)
{
    // lds[buf][{0:XH,1:XL,2:WH,3:WL}][row][k]
    __shared__ __align__(16) short lds[2][4][BM][PAD];   // 73728 B

    const int t  = threadIdx.x;
    const int w  = t >> 6;        // wave 0..3 -> token strip w*16..+15
    const int l  = t & 63;
    const int kh = blockIdx.x & 1;
    const long tok0 = (long)(blockIdx.x >> 1) * BM;
    const long kb0  = (long)kh * KHALF;

    const int sr = t >> 4;        // staging row base 0..15
    const int sc = (t & 15) * 4;  // staging k column (elems)

    f32x4 acc[4];
    #pragma unroll
    for (int nt = 0; nt < 4; ++nt) acc[nt] = (f32x4){0.f, 0.f, 0.f, 0.f};

    float4 xr[4], wr[4];

    auto LOADCH = [&](int ic) {
        const long k0 = kb0 + (long)ic * KC;
        #pragma unroll
        for (int p = 0; p < 4; ++p) {
            xr[p] = *(const float4*)(x + (tok0 + sr + 16 * p) * D_MODEL + k0 + sc);
            wr[p] = *(const float4*)(W + (long)(sr + 16 * p) * D_MODEL + k0 + sc);
        }
    };

    auto STORECH = [&](int buf) {
        #pragma unroll
        for (int p = 0; p < 4; ++p) {
            const int row = sr + 16 * p;
            const float fx[4] = {xr[p].x, xr[p].y, xr[p].z, xr[p].w};
            const float fw[4] = {wr[p].x, wr[p].y, wr[p].z, wr[p].w};
            short xh[4], xl[4], wh[4], wl[4];
            #pragma unroll
            for (int j = 0; j < 4; ++j) {
                __hip_bfloat16 h = __float2bfloat16(fx[j]);
                xh[j] = __builtin_bit_cast(short, h);
                xl[j] = __builtin_bit_cast(short, __float2bfloat16(fx[j] - __bfloat162float(h)));
                __hip_bfloat16 g = __float2bfloat16(fw[j]);
                wh[j] = __builtin_bit_cast(short, g);
                wl[j] = __builtin_bit_cast(short, __float2bfloat16(fw[j] - __bfloat162float(g)));
            }
            *(short4*)(&lds[buf][0][row][sc]) = make_short4(xh[0], xh[1], xh[2], xh[3]);
            *(short4*)(&lds[buf][1][row][sc]) = make_short4(xl[0], xl[1], xl[2], xl[3]);
            *(short4*)(&lds[buf][2][row][sc]) = make_short4(wh[0], wh[1], wh[2], wh[3]);
            *(short4*)(&lds[buf][3][row][sc]) = make_short4(wl[0], wl[1], wl[2], wl[3]);
        }
    };

    auto COMPUTE = [&](int buf) {
        const int arow = w * 16 + (l & 15);
        #pragma unroll
        for (int s = 0; s < 2; ++s) {
            const int ke = s * 32 + (l >> 4) * 8;
            short8_t ah = *(const short8_t*)(&lds[buf][0][arow][ke]);
            short8_t al = *(const short8_t*)(&lds[buf][1][arow][ke]);
            #pragma unroll
            for (int nt = 0; nt < 4; ++nt) {
                const int brow = nt * 16 + (l & 15);
                short8_t bh = *(const short8_t*)(&lds[buf][2][brow][ke]);
                short8_t bl = *(const short8_t*)(&lds[buf][3][brow][ke]);
                acc[nt] = __builtin_amdgcn_mfma_f32_16x16x32_bf16(ah, bl, acc[nt], 0, 0, 0);
                acc[nt] = __builtin_amdgcn_mfma_f32_16x16x32_bf16(al, bh, acc[nt], 0, 0, 0);
                acc[nt] = __builtin_amdgcn_mfma_f32_16x16x32_bf16(ah, bh, acc[nt], 0, 0, 0);
            }
        }
    };

    LOADCH(0);
    STORECH(0);
    __syncthreads();

    for (int ic = 0; ic < NCH; ++ic) {
        const int buf = ic & 1;
        const bool pre = (ic + 1 < NCH);
        if (pre) LOADCH(ic + 1);     // issue early: in flight during COMPUTE
        COMPUTE(buf);
        if (pre) STORECH(buf ^ 1);   // other buffer: no reader this iteration
        __syncthreads();             // single barrier per chunk
    }

    // partial store: token = w*16 + (l>>4)*4 + r, expert = nt*16 + (l&15)
    float* dst = kh ? p1 : p0;
    #pragma unroll
    for (int nt = 0; nt < 4; ++nt)
        #pragma unroll
        for (int r = 0; r < 4; ++r)
            dst[(tok0 + w * 16 + (l >> 4) * 4 + r) * NEXP + nt * 16 + (l & 15)] = acc[nt][r];
}

// -------- K2: combine + top-3 + flags + inline fp64 repair + gates + cnt ------
__global__ __launch_bounds__(256, 1)
void router_combine(const float* __restrict__ x, const float* __restrict__ W,
                    const float* __restrict__ p0, const float* __restrict__ p1,
                    float* __restrict__ out, float* __restrict__ cntp)
{
    __shared__ float L[64][65];
    __shared__ int   s_i0[64], s_i1[64];
    __shared__ float s_g0[64], s_g1[64];
    __shared__ unsigned long long s_mask;
    __shared__ double red[4][NEXP];

    const int t = threadIdx.x;
    const long tok0 = (long)blockIdx.x * 64;
    const int r = t >> 2, q = t & 3;

    // sum the two K-half partials -> logits in LDS
    {
        const float4* a4 = (const float4*)(p0 + (tok0 + r) * NEXP);
        const float4* b4 = (const float4*)(p1 + (tok0 + r) * NEXP);
        #pragma unroll
        for (int j = 0; j < 4; ++j) {
            float4 a = a4[q * 4 + j], b = b4[q * 4 + j];
            float* Lp = &L[r][q * 16 + j * 4];
            Lp[0] = a.x + b.x; Lp[1] = a.y + b.y; Lp[2] = a.z + b.z; Lp[3] = a.w + b.w;
        }
    }
    __syncthreads();

    // top-3 scan per token
    if (t < 64) {
        float b0 = -1e30f, b1 = -1e30f, b2 = -1e30f;
        int i0 = 0, i1 = 0;
        for (int e = 0; e < NEXP; ++e) {
            float v = L[t][e];
            if (v > b0)      { b2 = b1; b1 = b0; i1 = i0; b0 = v; i0 = e; }
            else if (v > b1) { b2 = b1; b1 = v; i1 = e; }
            else if (v > b2) { b2 = v; }
        }
        float ex = __expf(b1 - b0);
        float g0 = 1.f / (1.f + ex);
        s_i0[t] = i0; s_i1[t] = i1; s_g0[t] = g0; s_g1[t] = ex * g0;
        bool fl = (b0 - b1 < TAU) || (b1 - b2 < TAU);
        unsigned long long m = __ballot(fl);
        if (t == 0) s_mask = m;
    }
    __syncthreads();

    // fp64 repair of flagged tokens (rare; block-uniform loop)
    unsigned long long mask = s_mask;
    while (mask) {
        const int tt = __builtin_ctzll(mask);
        mask &= mask - 1;
        const long tok = tok0 + tt;
        const int e = t & 63, part = t >> 6;
        const float* xr = x + tok * D_MODEL;
        const float* wr = W + (long)e * D_MODEL;
        const int k0 = part * 512;
        double s = 0.0;
        for (int i = 0; i < 512; i += 4) {
            float4 xv = *(const float4*)(xr + k0 + i);
            float4 wv = *(const float4*)(wr + k0 + i);
            s = fma((double)xv.x, (double)wv.x, s);
            s = fma((double)xv.y, (double)wv.y, s);
            s = fma((double)xv.z, (double)wv.z, s);
            s = fma((double)xv.w, (double)wv.w, s);
        }
        red[part][e] = s;
        __syncthreads();
        if (t == 0) {
            double best = -1e300, sec = -1e300;
            int bi = 0, si = 0;
            for (int ee = 0; ee < NEXP; ++ee) {
                double vv = red[0][ee] + red[1][ee] + red[2][ee] + red[3][ee];
                if (vv > best)     { sec = best; si = bi; best = vv; bi = ee; }
                else if (vv > sec) { sec = vv; si = ee; }
            }
            double ex  = exp(sec - best);
            double inv = 1.0 / (1.0 + ex);
            s_i0[tt] = bi; s_i1[tt] = si;
            s_g0[tt] = (float)inv; s_g1[tt] = (float)(ex * inv);
        }
        __syncthreads();
    }

    // indices
    if (t < 64) {
        long tok = tok0 + t;
        out[IDX_OFF + 2 * tok]     = (float)s_i0[t];
        out[IDX_OFF + 2 * tok + 1] = (float)s_i1[t];
    }

    // dense gates: 4 lanes per token, 16 floats each
    {
        const int gi0 = s_i0[r], gi1 = s_i1[r];
        const float g0 = s_g0[r], g1 = s_g1[r];
        float* orow = out + (tok0 + r) * NEXP + q * 16;
        #pragma unroll
        for (int j4 = 0; j4 < 4; ++j4) {
            float v[4];
            #pragma unroll
            for (int j = 0; j < 4; ++j) {
                int e = q * 16 + j4 * 4 + j;
                v[j] = (e == gi0) ? g0 : ((e == gi1) ? g1 : 0.f);
            }
            *(float4*)(orow + j4 * 4) = make_float4(v[0], v[1], v[2], v[3]);
        }
    }

    // deterministic per-block expert counts (broadcast reads, no atomics)
    if (t < 64) {
        float c = 0.f;
        for (int tt = 0; tt < 64; ++tt) {
            if (s_i0[tt] == t) c += s_g0[tt];
            if (s_i1[tt] == t) c += s_g1[tt];
        }
        cntp[blockIdx.x * NEXP + t] = c;
    }
}

// ---------------- K3: load-balance loss ----------------
__global__ void router_loss(const float* __restrict__ cntp, float* __restrict__ out)
{
    __shared__ double red[4][NEXP];
    const int t = threadIdx.x;          // 256
    const int e = t & 63, p = t >> 6;
    double s = 0.0;
    for (int b = 0; b < 64; ++b)
        s += (double)cntp[(p * 64 + b) * NEXP + e];
    red[p][e] = s;
    __syncthreads();
    if (t == 0) {
        double sc[NEXP], tot = 0.0;
        for (int i = 0; i < NEXP; ++i) {
            sc[i] = red[0][i] + red[1][i] + red[2][i] + red[3][i];
            tot += sc[i];
        }
        double loss = 0.0;
        for (int i = 0; i < NEXP; ++i) {
            double d = sc[i] / tot * (double)NEXP - 1.0;
            loss += d * d;
        }
        out[LOSS_OFF] = (float)(loss / NEXP);
    }
}

extern "C" void kernel_launch(void* const* d_in, const int* in_sizes, int n_in,
                              void* d_out, int out_size, void* d_ws, size_t ws_size,
                              hipStream_t stream)
{
    const float* x = (const float*)d_in[0];
    const float* W = (const float*)d_in[1];
    float* out  = (float*)d_out;
    float* ws   = (float*)d_ws;        // needs ~4.26 MB
    float* p0   = out;                 // kh=0 partial parks in gates region
    float* p1   = ws;                  // kh=1 partial
    float* cntp = ws + WS_CNT;

    router_gemm   <<<(TOK_TOTAL / BM) * 2, 256, 0, stream>>>(x, W, p0, p1);
    router_combine<<<TOK_TOTAL / 64, 256, 0, stream>>>(x, W, p0, p1, out, cntp);
    router_loss   <<<1, 256, 0, stream>>>(cntp, out);
}

// Round 8
// 82.833 us; speedup vs baseline: 4.6509x; 1.5526x over previous
//
#include <hip/hip_runtime.h>
#include <hip/hip_bf16.h>
#include <math.h>

#define TOK_TOTAL 16384
#define D_MODEL   2048
#define NEXP      64
#define BM        64               // tokens per gemm block
#define KC        64               // k per LDS chunk
#define KHALF     1024             // split-K: half of K per block
#define NCH       (KHALF / KC)     // 16
#define PAD       72               // bf16 elems per LDS row
#define TAU       1e-3f

#define IDX_OFF   (TOK_TOTAL * NEXP)
#define LOSS_OFF  (IDX_OFF + TOK_TOTAL * 2)

// ws layout (floats): p1 [16384*64] | cntp [256*64] | rep_cnt [1] | rep_list [16384]
#define WS_CNT    (TOK_TOTAL * NEXP)
#define WS_RCNT   (WS_CNT + TOK_TOTAL)
#define WS_RLIST  (WS_RCNT + 1)

typedef __attribute__((ext_vector_type(8))) short short8_t;
typedef __attribute__((ext_vector_type(4))) float f32x4;

// ---------------- K1: split-bf16 MFMA GEMM, split-K x2 (unchanged) -----------
__global__ __launch_bounds__(256, 2)
void router_gemm(const float* __restrict__ x, const float* __restrict__ W,
                 float* __restrict__ p0, float* __restrict__ p1)
{
    __shared__ __align__(16) short lds[2][4][BM][PAD];   // 73728 B

    const int t  = threadIdx.x;
    const int w  = t >> 6;
    const int l  = t & 63;
    const int kh = blockIdx.x & 1;
    const long tok0 = (long)(blockIdx.x >> 1) * BM;
    const long kb0  = (long)kh * KHALF;

    const int sr = t >> 4;
    const int sc = (t & 15) * 4;

    f32x4 acc[4];
    #pragma unroll
    for (int nt = 0; nt < 4; ++nt) acc[nt] = (f32x4){0.f, 0.f, 0.f, 0.f};

    float4 xr[4], wr[4];

    auto LOADCH = [&](int ic) {
        const long k0 = kb0 + (long)ic * KC;
        #pragma unroll
        for (int p = 0; p < 4; ++p) {
            xr[p] = *(const float4*)(x + (tok0 + sr + 16 * p) * D_MODEL + k0 + sc);
            wr[p] = *(const float4*)(W + (long)(sr + 16 * p) * D_MODEL + k0 + sc);
        }
    };

    auto STORECH = [&](int buf) {
        #pragma unroll
        for (int p = 0; p < 4; ++p) {
            const int row = sr + 16 * p;
            const float fx[4] = {xr[p].x, xr[p].y, xr[p].z, xr[p].w};
            const float fw[4] = {wr[p].x, wr[p].y, wr[p].z, wr[p].w};
            short xh[4], xl[4], wh[4], wl[4];
            #pragma unroll
            for (int j = 0; j < 4; ++j) {
                __hip_bfloat16 h = __float2bfloat16(fx[j]);
                xh[j] = __builtin_bit_cast(short, h);
                xl[j] = __builtin_bit_cast(short, __float2bfloat16(fx[j] - __bfloat162float(h)));
                __hip_bfloat16 g = __float2bfloat16(fw[j]);
                wh[j] = __builtin_bit_cast(short, g);
                wl[j] = __builtin_bit_cast(short, __float2bfloat16(fw[j] - __bfloat162float(g)));
            }
            *(short4*)(&lds[buf][0][row][sc]) = make_short4(xh[0], xh[1], xh[2], xh[3]);
            *(short4*)(&lds[buf][1][row][sc]) = make_short4(xl[0], xl[1], xl[2], xl[3]);
            *(short4*)(&lds[buf][2][row][sc]) = make_short4(wh[0], wh[1], wh[2], wh[3]);
            *(short4*)(&lds[buf][3][row][sc]) = make_short4(wl[0], wl[1], wl[2], wl[3]);
        }
    };

    auto COMPUTE = [&](int buf) {
        const int arow = w * 16 + (l & 15);
        #pragma unroll
        for (int s = 0; s < 2; ++s) {
            const int ke = s * 32 + (l >> 4) * 8;
            short8_t ah = *(const short8_t*)(&lds[buf][0][arow][ke]);
            short8_t al = *(const short8_t*)(&lds[buf][1][arow][ke]);
            #pragma unroll
            for (int nt = 0; nt < 4; ++nt) {
                const int brow = nt * 16 + (l & 15);
                short8_t bh = *(const short8_t*)(&lds[buf][2][brow][ke]);
                short8_t bl = *(const short8_t*)(&lds[buf][3][brow][ke]);
                acc[nt] = __builtin_amdgcn_mfma_f32_16x16x32_bf16(ah, bl, acc[nt], 0, 0, 0);
                acc[nt] = __builtin_amdgcn_mfma_f32_16x16x32_bf16(al, bh, acc[nt], 0, 0, 0);
                acc[nt] = __builtin_amdgcn_mfma_f32_16x16x32_bf16(ah, bh, acc[nt], 0, 0, 0);
            }
        }
    };

    LOADCH(0);
    STORECH(0);
    __syncthreads();

    for (int ic = 0; ic < NCH; ++ic) {
        const int buf = ic & 1;
        const bool pre = (ic + 1 < NCH);
        if (pre) LOADCH(ic + 1);
        COMPUTE(buf);
        if (pre) STORECH(buf ^ 1);
        __syncthreads();
    }

    float* dst = kh ? p1 : p0;
    #pragma unroll
    for (int nt = 0; nt < 4; ++nt)
        #pragma unroll
        for (int r = 0; r < 4; ++r)
            dst[(tok0 + w * 16 + (l >> 4) * 4 + r) * NEXP + nt * 16 + (l & 15)] = acc[nt][r];
}

// -------- K2 v2: all-register combine: top-3 via shfl merge, no inline repair --
__global__ __launch_bounds__(256, 1)
void router_combine(const float* __restrict__ p0, const float* __restrict__ p1,
                    float* __restrict__ out, float* __restrict__ cntp,
                    int* __restrict__ rep_cnt, int* __restrict__ rep_list)
{
    __shared__ float4 s_ig[64];      // (i0, i1, g0, g1) per token
    const int t = threadIdx.x;
    const int r = t >> 2, q = t & 3;
    const long tok0 = (long)blockIdx.x * 64;
    const long tok  = tok0 + r;

    // my 16-expert quarter, fully in registers
    float v[16];
    {
        const float4* a4 = (const float4*)(p0 + tok * NEXP) + q * 4;
        const float4* b4 = (const float4*)(p1 + tok * NEXP) + q * 4;
        #pragma unroll
        for (int j = 0; j < 4; ++j) {
            float4 a = a4[j], b = b4[j];
            v[j*4+0] = a.x + b.x; v[j*4+1] = a.y + b.y;
            v[j*4+2] = a.z + b.z; v[j*4+3] = a.w + b.w;
        }
    }

    // local top-3 (indices for top-2), ascending e => ties keep lower index
    float b0 = -1e30f, b1 = -1e30f, b2 = -1e30f;
    int i0 = 0, i1 = 0;
    const int ebase = q * 16;
    #pragma unroll
    for (int j = 0; j < 16; ++j) {
        float xv = v[j]; int e = ebase + j;
        if (xv > b0)      { b2 = b1; b1 = b0; i1 = i0; b0 = xv; i0 = e; }
        else if (xv > b1) { b2 = b1; b1 = xv; i1 = e; }
        else if (xv > b2) { b2 = xv; }
    }

    // merge across the 4 lanes of this token (xor 1, then xor 2)
    #pragma unroll
    for (int d = 1; d <= 2; d <<= 1) {
        float ob0 = __shfl_xor(b0, d, 64), ob1 = __shfl_xor(b1, d, 64), ob2 = __shfl_xor(b2, d, 64);
        int   oi0 = __shfl_xor(i0, d, 64), oi1 = __shfl_xor(i1, d, 64);
        bool a0w = (b0 > ob0) || (b0 == ob0 && i0 < oi0);
        float nb0 = a0w ? b0 : ob0;  int ni0 = a0w ? i0 : oi0;
        float ca  = a0w ? b1 : ob1;  int cia = a0w ? i1 : oi1;   // winner's 2nd
        float cb  = a0w ? ob0 : b0;  int cib = a0w ? oi0 : i0;   // loser's 1st
        float wa2 = a0w ? b2 : ob2;                              // winner's 3rd
        float lb1 = a0w ? ob1 : b1;                              // loser's 2nd
        bool w1 = (ca > cb) || (ca == cb && cia < cib);
        float nb1 = w1 ? ca : cb;  int ni1 = w1 ? cia : cib;
        float nb2 = w1 ? fmaxf(wa2, cb) : fmaxf(ca, lb1);
        b0 = nb0; i0 = ni0; b1 = nb1; i1 = ni1; b2 = nb2;
    }

    float ex = __expf(b1 - b0);
    float g0 = 1.f / (1.f + ex);
    float g1 = ex * g0;

    // gates quarter from registers
    {
        float* orow = out + tok * NEXP + ebase;
        #pragma unroll
        for (int j4 = 0; j4 < 4; ++j4) {
            float gv[4];
            #pragma unroll
            for (int j = 0; j < 4; ++j) {
                int e = ebase + j4 * 4 + j;
                gv[j] = (e == i0) ? g0 : ((e == i1) ? g1 : 0.f);
            }
            *(float4*)(orow + j4 * 4) = make_float4(gv[0], gv[1], gv[2], gv[3]);
        }
    }

    if (q == 0) {
        out[IDX_OFF + 2 * tok]     = (float)i0;
        out[IDX_OFF + 2 * tok + 1] = (float)i1;
        s_ig[r] = make_float4((float)i0, (float)i1, g0, g1);
        if ((b0 - b1 < TAU) || (b1 - b2 < TAU)) {
            int p = atomicAdd(rep_cnt, 1);
            rep_list[p] = (int)tok;
        }
    }
    __syncthreads();

    if (t < 64) {
        float c = 0.f;
        for (int tt = 0; tt < 64; ++tt) {
            float4 gg = s_ig[tt];
            if ((int)gg.x == t) c += gg.z;
            if ((int)gg.y == t) c += gg.w;
        }
        cntp[blockIdx.x * NEXP + t] = c;
    }
}

// -------- K3: fp64 index repair, one block per flagged token (grid-stride) ----
__global__ __launch_bounds__(256, 1)
void router_repair(const float* __restrict__ x, const float* __restrict__ W,
                   float* __restrict__ out,
                   const int* __restrict__ rep_cnt, const int* __restrict__ rep_list)
{
    __shared__ double red[4][NEXP];
    const int nf = *rep_cnt;
    const int t = threadIdx.x;
    const int e = t & 63, part = t >> 6;

    for (int i = blockIdx.x; i < nf; i += gridDim.x) {
        const long tok = rep_list[i];
        const float* xr = x + tok * D_MODEL;
        const float* wr = W + (long)e * D_MODEL;
        const int k0 = part * 512;
        double s = 0.0;
        for (int kk = 0; kk < 512; kk += 4) {
            float4 xv = *(const float4*)(xr + k0 + kk);
            float4 wv = *(const float4*)(wr + k0 + kk);
            s = fma((double)xv.x, (double)wv.x, s);
            s = fma((double)xv.y, (double)wv.y, s);
            s = fma((double)xv.z, (double)wv.z, s);
            s = fma((double)xv.w, (double)wv.w, s);
        }
        red[part][e] = s;
        __syncthreads();
        if (t == 0) {
            double best = -1e300, sec = -1e300;
            int bi = 0, si = 0;
            for (int ee = 0; ee < NEXP; ++ee) {
                double vv = red[0][ee] + red[1][ee] + red[2][ee] + red[3][ee];
                if (vv > best)     { sec = best; si = bi; best = vv; bi = ee; }
                else if (vv > sec) { sec = vv; si = ee; }
            }
            out[IDX_OFF + 2 * tok]     = (float)bi;
            out[IDX_OFF + 2 * tok + 1] = (float)si;
        }
        __syncthreads();
    }
}

// ---------------- K4: load-balance loss ----------------
__global__ void router_loss(const float* __restrict__ cntp, float* __restrict__ out)
{
    __shared__ double red[4][NEXP];
    const int t = threadIdx.x;          // 256
    const int e = t & 63, p = t >> 6;
    double s = 0.0;
    for (int b = 0; b < 64; ++b)
        s += (double)cntp[(p * 64 + b) * NEXP + e];
    red[p][e] = s;
    __syncthreads();
    if (t == 0) {
        double sc[NEXP], tot = 0.0;
        for (int i = 0; i < NEXP; ++i) {
            sc[i] = red[0][i] + red[1][i] + red[2][i] + red[3][i];
            tot += sc[i];
        }
        double loss = 0.0;
        for (int i = 0; i < NEXP; ++i) {
            double d = sc[i] / tot * (double)NEXP - 1.0;
            loss += d * d;
        }
        out[LOSS_OFF] = (float)(loss / NEXP);
    }
}

extern "C" void kernel_launch(void* const* d_in, const int* in_sizes, int n_in,
                              void* d_out, int out_size, void* d_ws, size_t ws_size,
                              hipStream_t stream)
{
    const float* x = (const float*)d_in[0];
    const float* W = (const float*)d_in[1];
    float* out  = (float*)d_out;
    float* ws   = (float*)d_ws;        // ~4.33 MB used
    float* p0   = out;                 // kh=0 partial parks in gates region
    float* p1   = ws;                  // kh=1 partial
    float* cntp = ws + WS_CNT;
    int*   rep_cnt  = (int*)(ws + WS_RCNT);
    int*   rep_list = (int*)(ws + WS_RLIST);

    hipMemsetAsync(rep_cnt, 0, sizeof(int), stream);
    router_gemm   <<<(TOK_TOTAL / BM) * 2, 256, 0, stream>>>(x, W, p0, p1);
    router_combine<<<TOK_TOTAL / 64, 256, 0, stream>>>(p0, p1, out, cntp, rep_cnt, rep_list);
    router_repair <<<256, 256, 0, stream>>>(x, W, out, rep_cnt, rep_list);
    router_loss   <<<1, 256, 0, stream>>>(cntp, out);
}